// Round 16
// baseline (26.899 us; speedup 1.0000x reference)
//
#include <hip/hip_runtime.h>
#include <stdint.h>

#define Bn 512
#define Tn 512
#define Ln 48
#define Cn 128
#define BLANKC 127
#define EPSf 1e-7f
#define LN2f 0.6931471805599453f

// f32 DPP, 0-fill OOB (bound_ctrl=1)
template<int CTRL>
__device__ __forceinline__ float dpp_f0(float x) {
    int r = __builtin_amdgcn_update_dpp(0, __float_as_int(x), CTRL, 0xF, 0xF, true);
    return __int_as_float(r);
}
// int DPP, keep-self OOB (identity for max-reduce)
template<int CTRL>
__device__ __forceinline__ int dpp_i_keep(int x) {
    return __builtin_amdgcn_update_dpp(x, x, CTRL, 0xF, 0xF, false);
}
// f64 DPP, 0-fill OOB: move both 32-bit halves identically (pure lane permute)
template<int CTRL>
__device__ __forceinline__ double dpp64_f0(double x) {
    long long v = __double_as_longlong(x);
    int lo = (int)(v & 0xffffffffLL);
    int hi = (int)(v >> 32);
    lo = __builtin_amdgcn_update_dpp(0, lo, CTRL, 0xF, 0xF, true);
    hi = __builtin_amdgcn_update_dpp(0, hi, CTRL, 0xF, 0xF, true);
    return __longlong_as_double(((long long)(unsigned int)lo) | ((long long)hi << 32));
}
// 0x138 wave_shr:1 ; 0x130 wave_shl:1 ; 0x111/2/4/8 row_shr:1/2/4/8

__global__ void __launch_bounds__(128, 1) ctc_fwd(
        const int* __restrict__ yt,
        const float* __restrict__ yp,
        float* __restrict__ out)
{
    const int b = blockIdx.x;
    const int w = threadIdx.x >> 6;   // 0 = forward wave, 1 = backward wave
    const int l = threadIdx.x & 63;

    __shared__ float  ring[2][8192];  // per-wave ring: 4 slots x 16 rows x 128 cols
    __shared__ double xb0d[64], xb1d[64];
    __shared__ int    xEbs;
    __shared__ int    rnmax[2][4];
    __shared__ double rsumd[4];

    const bool lab_ok = (l < Ln);
    int  cls1 = BLANKC;
    bool allow2 = false;
    if (lab_ok) {
        cls1 = yt[b * Ln + l];
        if (l >= 1) allow2 = (cls1 != yt[b * Ln + l - 1]);
    }
    const double mA = allow2 ? 1.0 : 0.0;

    double a0, a1;           // f64 linear alphas/betas, wave-uniform scale 2^E
    int    E = 0;
    float* lds = &ring[w][0];
    const float* gbase = yp + (size_t)b * (Tn * Cn);

#define STAGE(FIRSTROW, SLOTBASE)                                            \
    {                                                                        \
        const float* gr_ = gbase + (size_t)(FIRSTROW) * Cn + (l << 2);       \
        _Pragma("unroll")                                                    \
        for (int j = 0; j < 8; ++j)                                          \
            __builtin_amdgcn_global_load_lds(                                \
                (const __attribute__((address_space(1))) uint32_t*)(gr_ + j * 256), \
                (__attribute__((address_space(3))) uint32_t*)&lds[(SLOTBASE) + j * 256], \
                16, 0, 0);                                                   \
    }

#define WAIT16() asm volatile("s_waitcnt vmcnt(16)" ::: "memory");
#define WAIT8()  asm volatile("s_waitcnt vmcnt(8)"  ::: "memory");
#define WAIT0()  asm volatile("s_waitcnt vmcnt(0)"  ::: "memory");

#define RENORM64()                                                   \
    {                                                                \
        int h0_ = (int)(__double_as_longlong(a0) >> 32);             \
        int h1_ = (int)(__double_as_longlong(a1) >> 32);             \
        int mh_ = max(h0_, h1_);                                     \
        mh_ = max(mh_, dpp_i_keep<0x111>(mh_));                      \
        mh_ = max(mh_, dpp_i_keep<0x112>(mh_));                      \
        mh_ = max(mh_, dpp_i_keep<0x114>(mh_));                      \
        mh_ = max(mh_, dpp_i_keep<0x118>(mh_));                      \
        if ((l & 15) == 15) rnmax[w][l >> 4] = mh_;                  \
        int g_ = max(max(rnmax[w][0], rnmax[w][1]),                  \
                     max(rnmax[w][2], rnmax[w][3]));                 \
        int e_ = ((g_ >> 20) & 0x7FF) - 1022;                        \
        double sc_ = __longlong_as_double((long long)(1023 - e_) << 52); \
        a0 *= sc_; a1 *= sc_;                                        \
        E += e_;                                                     \
    }

    if (w == 0) {
        // ============ FORWARD: alpha_0 -> alpha_255 (255 steps) ===========
        // prolog: stage chunks 0..3 (lead = 3 completed + in-flight)
        STAGE(0, 0) STAGE(16, 2048) STAGE(32, 4096) STAGE(48, 6144)
        WAIT16()   // chunks 0,1 resident

        a0 = (l == 0) ? (double)(lds[127]  + EPSf) : 0.0;
        a1 = (l == 0) ? (double)(lds[cls1] + EPSf) : 0.0;

        float pb1 = lds[(1 << 7) + 127], pl1 = lds[(1 << 7) + cls1];
        float pb2 = lds[(2 << 7) + 127], pl2 = lds[(2 << 7) + cls1];
        float pb3 = lds[(3 << 7) + 127], pl3 = lds[(3 << 7) + cls1];
        float pb0 = lds[(4 << 7) + 127], pl0 = lds[(4 << 7) + cls1];

#define FSTEP(PB, PL, LID, dopf)                                     \
    {                                                                \
        float nb_ = 0.0f, nl_ = 0.0f;                                \
        if (dopf) { nb_ = lds[(LID) + 127];                          \
                    nl_ = lds[(LID) + cls1]; }                       \
        float f0_ = (PB) + EPSf;                                     \
        float f1_ = lab_ok ? (PL) + EPSf : 0.0f;                     \
        double p0 = (double)f0_;                                     \
        double p1 = (double)f1_;                                     \
        double h1 = dpp64_f0<0x138>(a1);                             \
        double s01 = a0 + a1;                                        \
        double t0 = a0 + h1;                                         \
        double u  = fma(mA, h1, s01);                                \
        a0 = t0 * p0;                                                \
        a1 = u * p1;                                                 \
        if (dopf) { (PB) = nb_; (PL) = nl_; }                        \
    }

        // ---- chunk 0: t = 1..15 ----
        FSTEP(pb1, pl1, (5 << 7), true)
        FSTEP(pb2, pl2, (6 << 7), true)
        FSTEP(pb3, pl3, (7 << 7), true)
        FSTEP(pb0, pl0, (8 << 7), true)
        FSTEP(pb1, pl1, (9 << 7), true)
        FSTEP(pb2, pl2, (10 << 7), true)
        FSTEP(pb3, pl3, (11 << 7), true)
        FSTEP(pb0, pl0, (12 << 7), true)
        FSTEP(pb1, pl1, (13 << 7), true)
        FSTEP(pb2, pl2, (14 << 7), true)
        FSTEP(pb3, pl3, (15 << 7), true)
        FSTEP(pb0, pl0, 2048 + (0 << 7), true)
        FSTEP(pb1, pl1, 2048 + (1 << 7), true)
        FSTEP(pb2, pl2, 2048 + (2 << 7), true)
        FSTEP(pb3, pl3, 2048 + (3 << 7), true)
        RENORM64()
        STAGE(64, 0) WAIT16()   // boundary 0: chunk 4 -> just-freed slot 0

#define F16(IB, INX)                                                 \
        FSTEP(pb0, pl0, (IB) + (4 << 7), true)                       \
        FSTEP(pb1, pl1, (IB) + (5 << 7), true)                       \
        FSTEP(pb2, pl2, (IB) + (6 << 7), true)                       \
        FSTEP(pb3, pl3, (IB) + (7 << 7), true)                       \
        FSTEP(pb0, pl0, (IB) + (8 << 7), true)                       \
        FSTEP(pb1, pl1, (IB) + (9 << 7), true)                       \
        FSTEP(pb2, pl2, (IB) + (10 << 7), true)                      \
        FSTEP(pb3, pl3, (IB) + (11 << 7), true)                      \
        FSTEP(pb0, pl0, (IB) + (12 << 7), true)                      \
        FSTEP(pb1, pl1, (IB) + (13 << 7), true)                      \
        FSTEP(pb2, pl2, (IB) + (14 << 7), true)                      \
        FSTEP(pb3, pl3, (IB) + (15 << 7), true)                      \
        FSTEP(pb0, pl0, (INX) + (0 << 7), true)                      \
        FSTEP(pb1, pl1, (INX) + (1 << 7), true)                      \
        FSTEP(pb2, pl2, (INX) + (2 << 7), true)                      \
        FSTEP(pb3, pl3, (INX) + (3 << 7), true)                      \
        RENORM64()

        // chunks 1..11: consume, stage chunk c+4 into freed slot, WAIT16
        for (int c = 1; c <= 11; ++c) {
            const int ib  = (c & 3) << 11;
            const int inx = ((c + 1) & 3) << 11;
            F16(ib, inx)
            STAGE((c + 4) * 16, ib)
            WAIT16()
        }
        F16(0 << 11, 1 << 11)       // chunk 12
        WAIT8()                      // chunk 14 resident
        F16(1 << 11, 2 << 11)       // chunk 13
        WAIT0()                      // chunk 15 resident
        F16(2 << 11, 3 << 11)       // chunk 14
        {                            // chunk 15: t = 240..255
            const int ib = 3 << 11;
            FSTEP(pb0, pl0, ib + (4 << 7), true)
            FSTEP(pb1, pl1, ib + (5 << 7), true)
            FSTEP(pb2, pl2, ib + (6 << 7), true)
            FSTEP(pb3, pl3, ib + (7 << 7), true)
            FSTEP(pb0, pl0, ib + (8 << 7), true)
            FSTEP(pb1, pl1, ib + (9 << 7), true)
            FSTEP(pb2, pl2, ib + (10 << 7), true)
            FSTEP(pb3, pl3, ib + (11 << 7), true)
            FSTEP(pb0, pl0, ib + (12 << 7), true)
            FSTEP(pb1, pl1, ib + (13 << 7), true)
            FSTEP(pb2, pl2, ib + (14 << 7), true)
            FSTEP(pb3, pl3, ib + (15 << 7), true)
            FSTEP(pb0, pl0, 0, false)
            FSTEP(pb1, pl1, 0, false)
            FSTEP(pb2, pl2, 0, false)
            FSTEP(pb3, pl3, 0, false)
            RENORM64()
        }
#undef FSTEP
#undef F16
    } else {
        // ============ BACKWARD: beta_511 -> beta_255 (256 steps) ==========
        STAGE(496, 0) STAGE(480, 2048) STAGE(464, 4096) STAGE(448, 6144)
        WAIT16()

        a0 = (l == 48) ? 1.0 : 0.0;   // beta[2l]
        a1 = (l == 47) ? 1.0 : 0.0;   // beta[2l+1]

        float pb0 = lds[(15 << 7) + 127], pl0 = lds[(15 << 7) + cls1];
        float pb1 = lds[(14 << 7) + 127], pl1 = lds[(14 << 7) + cls1];
        float pb2 = lds[(13 << 7) + 127], pl2 = lds[(13 << 7) + cls1];
        float pb3 = lds[(12 << 7) + 127], pl3 = lds[(12 << 7) + cls1];

#define BSTEP(PB, PL, LID, dopf)                                     \
    {                                                                \
        float nb_ = 0.0f, nl_ = 0.0f;                                \
        if (dopf) { nb_ = lds[(LID) + 127];                          \
                    nl_ = lds[(LID) + cls1]; }                       \
        float f0_ = (PB) + EPSf;                                     \
        float f1_ = lab_ok ? (PL) + EPSf : 0.0f;                     \
        double p0 = (double)f0_;                                     \
        double p1 = (double)f1_;                                     \
        double g0 = a0 * p0;                                         \
        double g1 = a1 * p1;                                         \
        double pre = fma(mA, g1, g0);                                \
        double up = dpp64_f0<0x130>(pre);                            \
        a0 = g0 + g1;                                                \
        a1 = g1 + up;                                                \
        if (dopf) { (PB) = nb_; (PL) = nl_; }                        \
    }

#define B16(IB, INX)                                                 \
        BSTEP(pb0, pl0, (IB) + (11 << 7), true)                      \
        BSTEP(pb1, pl1, (IB) + (10 << 7), true)                      \
        BSTEP(pb2, pl2, (IB) + (9 << 7), true)                       \
        BSTEP(pb3, pl3, (IB) + (8 << 7), true)                       \
        BSTEP(pb0, pl0, (IB) + (7 << 7), true)                       \
        BSTEP(pb1, pl1, (IB) + (6 << 7), true)                       \
        BSTEP(pb2, pl2, (IB) + (5 << 7), true)                       \
        BSTEP(pb3, pl3, (IB) + (4 << 7), true)                       \
        BSTEP(pb0, pl0, (IB) + (3 << 7), true)                       \
        BSTEP(pb1, pl1, (IB) + (2 << 7), true)                       \
        BSTEP(pb2, pl2, (IB) + (1 << 7), true)                       \
        BSTEP(pb3, pl3, (IB) + (0 << 7), true)                       \
        BSTEP(pb0, pl0, (INX) + (15 << 7), true)                     \
        BSTEP(pb1, pl1, (INX) + (14 << 7), true)                     \
        BSTEP(pb2, pl2, (INX) + (13 << 7), true)                     \
        BSTEP(pb3, pl3, (INX) + (12 << 7), true)                     \
        RENORM64()

        B16(0, 2048)                 // chunk 0
        STAGE(432, 0) WAIT16()       // boundary 0: chunk 4 -> freed slot 0

        for (int c = 1; c <= 11; ++c) {
            const int ib  = (c & 3) << 11;
            const int inx = ((c + 1) & 3) << 11;
            B16(ib, inx)
            STAGE(496 - 16 * (c + 4), ib)
            WAIT16()
        }
        B16(0 << 11, 1 << 11)        // chunk 12
        WAIT8()
        B16(1 << 11, 2 << 11)        // chunk 13
        WAIT0()
        B16(2 << 11, 3 << 11)        // chunk 14
        {                            // chunk 15: rows 271..256
            const int ib = 3 << 11;
            BSTEP(pb0, pl0, ib + (11 << 7), true)
            BSTEP(pb1, pl1, ib + (10 << 7), true)
            BSTEP(pb2, pl2, ib + (9 << 7), true)
            BSTEP(pb3, pl3, ib + (8 << 7), true)
            BSTEP(pb0, pl0, ib + (7 << 7), true)
            BSTEP(pb1, pl1, ib + (6 << 7), true)
            BSTEP(pb2, pl2, ib + (5 << 7), true)
            BSTEP(pb3, pl3, ib + (4 << 7), true)
            BSTEP(pb0, pl0, ib + (3 << 7), true)
            BSTEP(pb1, pl1, ib + (2 << 7), true)
            BSTEP(pb2, pl2, ib + (1 << 7), true)
            BSTEP(pb3, pl3, ib + (0 << 7), true)
            BSTEP(pb0, pl0, 0, false)
            BSTEP(pb1, pl1, 0, false)
            BSTEP(pb2, pl2, 0, false)
            BSTEP(pb3, pl3, 0, false)
            RENORM64()
        }
#undef BSTEP
#undef B16

        xb0d[l] = a0; xb1d[l] = a1;
        if (l == 0) xEbs = E;
    }

    __syncthreads();

    if (w == 0) {
        double c = a0 * xb0d[l] + a1 * xb1d[l];
        c += dpp64_f0<0x111>(c);
        c += dpp64_f0<0x112>(c);
        c += dpp64_f0<0x114>(c);
        c += dpp64_f0<0x118>(c);
        if ((l & 15) == 15) rsumd[l >> 4] = c;
        if (l == 0) {
            double s = rsumd[0] + rsumd[1] + rsumd[2] + rsumd[3];
            long long sb = __double_as_longlong(s);
            int se = (int)((sb >> 52) & 0x7FF) - 1022;
            double m = __longlong_as_double((sb & 0x800FFFFFFFFFFFFFLL) | (1022LL << 52));
            float lg = __log2f((float)m) + (float)(se + E + xEbs);
            out[b] = -LN2f * lg;
        }
    }
#undef STAGE
#undef WAIT16
#undef WAIT8
#undef WAIT0
#undef RENORM64
}

extern "C" void kernel_launch(void* const* d_in, const int* in_sizes, int n_in,
                              void* d_out, int out_size, void* d_ws, size_t ws_size,
                              hipStream_t stream) {
    const int*   yt  = (const int*)d_in[0];
    const float* yp  = (const float*)d_in[1];
    float*       out = (float*)d_out;
    hipLaunchKernelGGL(ctc_fwd, dim3(Bn), dim3(128), 0, stream, yt, yp, out);
}

// Round 17
// 26.613 us; speedup vs baseline: 1.0107x; 1.0107x over previous
//
#include <hip/hip_runtime.h>
#include <stdint.h>

#define Bn 512
#define Tn 512
#define Ln 48
#define Cn 128
#define BLANKC 127
#define EPSf 1e-7f
#define LN2f 0.6931471805599453f

template<int CTRL>
__device__ __forceinline__ float dpp_f0(float x) {
    int r = __builtin_amdgcn_update_dpp(0, __float_as_int(x), CTRL, 0xF, 0xF, true);
    return __int_as_float(r);
}
template<int CTRL>
__device__ __forceinline__ int dpp_i_keep(int x) {
    return __builtin_amdgcn_update_dpp(x, x, CTRL, 0xF, 0xF, false);
}
template<int CTRL>
__device__ __forceinline__ double dpp64_f0(double x) {
    long long v = __double_as_longlong(x);
    int lo = (int)(v & 0xffffffffLL);
    int hi = (int)(v >> 32);
    lo = __builtin_amdgcn_update_dpp(0, lo, CTRL, 0xF, 0xF, true);
    hi = __builtin_amdgcn_update_dpp(0, hi, CTRL, 0xF, 0xF, true);
    return __longlong_as_double(((long long)(unsigned int)lo) | ((long long)hi << 32));
}
// 0x138 wave_shr:1 ; 0x130 wave_shl:1 ; 0x111/2/4/8 row_shr:1/2/4/8

__global__ void __launch_bounds__(128, 1) ctc_fwd(
        const int* __restrict__ yt,
        const float* __restrict__ yp,
        float* __restrict__ out)
{
    const int b = blockIdx.x;
    const int w = threadIdx.x >> 6;   // 0 = forward wave, 1 = backward wave
    const int l = threadIdx.x & 63;

    __shared__ float  ring[2][8192];  // per-wave: 4 slots x 16 rows x 128 cols
    __shared__ double xb0d[64], xb1d[64];
    __shared__ int    xEbs;
    __shared__ int    rnmax[2][4];
    __shared__ double rsumd[4];

    const bool lab_ok = (l < Ln);
    int  cls1 = BLANKC;
    bool allow2 = false;
    if (lab_ok) {
        cls1 = yt[b * Ln + l];
        if (l >= 1) allow2 = (cls1 != yt[b * Ln + l - 1]);
    }
    const double mA = allow2 ? 1.0 : 0.0;

    double a0, a1;
    int    E = 0;
    float* lds = &ring[w][0];
    const float* gbase = yp + (size_t)b * (Tn * Cn);

#define STAGE(FIRSTROW, SLOTBASE)                                            \
    {                                                                        \
        const float* gr_ = gbase + (size_t)(FIRSTROW) * Cn + (l << 2);       \
        _Pragma("unroll")                                                    \
        for (int j = 0; j < 8; ++j)                                          \
            __builtin_amdgcn_global_load_lds(                                \
                (const __attribute__((address_space(1))) uint32_t*)(gr_ + j * 256), \
                (__attribute__((address_space(3))) uint32_t*)&lds[(SLOTBASE) + j * 256], \
                16, 0, 0);                                                   \
    }

#define WAIT16() asm volatile("s_waitcnt vmcnt(16)" ::: "memory");
#define WAIT8()  asm volatile("s_waitcnt vmcnt(8)"  ::: "memory");
#define WAIT0()  asm volatile("s_waitcnt vmcnt(0)"  ::: "memory");

#define RENORM64()                                                   \
    {                                                                \
        int h0_ = (int)(__double_as_longlong(a0) >> 32);             \
        int h1_ = (int)(__double_as_longlong(a1) >> 32);             \
        int mh_ = max(h0_, h1_);                                     \
        mh_ = max(mh_, dpp_i_keep<0x111>(mh_));                      \
        mh_ = max(mh_, dpp_i_keep<0x112>(mh_));                      \
        mh_ = max(mh_, dpp_i_keep<0x114>(mh_));                      \
        mh_ = max(mh_, dpp_i_keep<0x118>(mh_));                      \
        if ((l & 15) == 15) rnmax[w][l >> 4] = mh_;                  \
        int g_ = max(max(rnmax[w][0], rnmax[w][1]),                  \
                     max(rnmax[w][2], rnmax[w][3]));                 \
        int e_ = ((g_ >> 20) & 0x7FF) - 1022;                        \
        double sc_ = __longlong_as_double((long long)(1023 - e_) << 52); \
        a0 *= sc_; a1 *= sc_;                                        \
        E += e_;                                                     \
    }

    if (w == 0) {
        // ============ FORWARD: alpha_0 -> alpha_255 (255 steps) ===========
        STAGE(0, 0) STAGE(16, 2048) STAGE(32, 4096) STAGE(48, 6144)
        WAIT16()   // chunks 0,1 resident

        a0 = (l == 0) ? (double)(lds[127]  + EPSf) : 0.0;
        a1 = (l == 0) ? (double)(lds[cls1] + EPSf) : 0.0;

        // 8-slot register rotation (slot = t&7); prime rows 1..8
        float pb1 = lds[(1 << 7) + 127], pl1 = lds[(1 << 7) + cls1];
        float pb2 = lds[(2 << 7) + 127], pl2 = lds[(2 << 7) + cls1];
        float pb3 = lds[(3 << 7) + 127], pl3 = lds[(3 << 7) + cls1];
        float pb4 = lds[(4 << 7) + 127], pl4 = lds[(4 << 7) + cls1];
        float pb5 = lds[(5 << 7) + 127], pl5 = lds[(5 << 7) + cls1];
        float pb6 = lds[(6 << 7) + 127], pl6 = lds[(6 << 7) + cls1];
        float pb7 = lds[(7 << 7) + 127], pl7 = lds[(7 << 7) + cls1];
        float pb0 = lds[(8 << 7) + 127], pl0 = lds[(8 << 7) + cls1];

#define FSTEP(PB, PL, LID, dopf)                                     \
    {                                                                \
        float nb_ = 0.0f, nl_ = 0.0f;                                \
        if (dopf) { nb_ = lds[(LID) + 127];                          \
                    nl_ = lds[(LID) + cls1]; }                       \
        float f0_ = (PB) + EPSf;                                     \
        float f1_ = lab_ok ? (PL) + EPSf : 0.0f;                     \
        double p0 = (double)f0_;                                     \
        double p1 = (double)f1_;                                     \
        double h1 = dpp64_f0<0x138>(a1);                             \
        double s01 = a0 + a1;                                        \
        double t0 = a0 + h1;                                         \
        double u  = fma(mA, h1, s01);                                \
        a0 = t0 * p0;                                                \
        a1 = u * p1;                                                 \
        if (dopf) { (PB) = nb_; (PL) = nl_; }                        \
    }

        // ---- chunk 0: t = 1..15, prefetch row t+8 ----
        FSTEP(pb1, pl1, (9 << 7), true)
        FSTEP(pb2, pl2, (10 << 7), true)
        FSTEP(pb3, pl3, (11 << 7), true)
        FSTEP(pb4, pl4, (12 << 7), true)
        FSTEP(pb5, pl5, (13 << 7), true)
        FSTEP(pb6, pl6, (14 << 7), true)
        FSTEP(pb7, pl7, (15 << 7), true)
        FSTEP(pb0, pl0, 2048 + (0 << 7), true)
        FSTEP(pb1, pl1, 2048 + (1 << 7), true)
        FSTEP(pb2, pl2, 2048 + (2 << 7), true)
        FSTEP(pb3, pl3, 2048 + (3 << 7), true)
        FSTEP(pb4, pl4, 2048 + (4 << 7), true)
        FSTEP(pb5, pl5, 2048 + (5 << 7), true)
        FSTEP(pb6, pl6, 2048 + (6 << 7), true)
        FSTEP(pb7, pl7, 2048 + (7 << 7), true)
        RENORM64()
        STAGE(64, 0) WAIT16()

        // chunk c steps r=0..15 (slot r&7): r<8 pf IB row r+8 ; r>=8 pf INX row r-8
#define F16(IB, INX)                                                 \
        FSTEP(pb0, pl0, (IB) + (8 << 7), true)                       \
        FSTEP(pb1, pl1, (IB) + (9 << 7), true)                       \
        FSTEP(pb2, pl2, (IB) + (10 << 7), true)                      \
        FSTEP(pb3, pl3, (IB) + (11 << 7), true)                      \
        FSTEP(pb4, pl4, (IB) + (12 << 7), true)                      \
        FSTEP(pb5, pl5, (IB) + (13 << 7), true)                      \
        FSTEP(pb6, pl6, (IB) + (14 << 7), true)                      \
        FSTEP(pb7, pl7, (IB) + (15 << 7), true)                      \
        FSTEP(pb0, pl0, (INX) + (0 << 7), true)                      \
        FSTEP(pb1, pl1, (INX) + (1 << 7), true)                      \
        FSTEP(pb2, pl2, (INX) + (2 << 7), true)                      \
        FSTEP(pb3, pl3, (INX) + (3 << 7), true)                      \
        FSTEP(pb4, pl4, (INX) + (4 << 7), true)                      \
        FSTEP(pb5, pl5, (INX) + (5 << 7), true)                      \
        FSTEP(pb6, pl6, (INX) + (6 << 7), true)                      \
        FSTEP(pb7, pl7, (INX) + (7 << 7), true)                      \
        RENORM64()

        for (int c = 1; c <= 11; ++c) {
            const int ib  = (c & 3) << 11;
            const int inx = ((c + 1) & 3) << 11;
            F16(ib, inx)
            STAGE((c + 4) * 16, ib)
            WAIT16()
        }
        F16(0 << 11, 1 << 11)       // chunk 12
        WAIT8()
        F16(1 << 11, 2 << 11)       // chunk 13
        WAIT0()
        F16(2 << 11, 3 << 11)       // chunk 14
        {                            // chunk 15: t = 240..255
            const int ib = 3 << 11;
            FSTEP(pb0, pl0, ib + (8 << 7), true)
            FSTEP(pb1, pl1, ib + (9 << 7), true)
            FSTEP(pb2, pl2, ib + (10 << 7), true)
            FSTEP(pb3, pl3, ib + (11 << 7), true)
            FSTEP(pb4, pl4, ib + (12 << 7), true)
            FSTEP(pb5, pl5, ib + (13 << 7), true)
            FSTEP(pb6, pl6, ib + (14 << 7), true)
            FSTEP(pb7, pl7, ib + (15 << 7), true)
            FSTEP(pb0, pl0, 0, false)
            FSTEP(pb1, pl1, 0, false)
            FSTEP(pb2, pl2, 0, false)
            FSTEP(pb3, pl3, 0, false)
            FSTEP(pb4, pl4, 0, false)
            FSTEP(pb5, pl5, 0, false)
            FSTEP(pb6, pl6, 0, false)
            RENORM64()
        }
#undef FSTEP
#undef F16
    } else {
        // ============ BACKWARD: beta_511 -> beta_255 (256 steps) ==========
        STAGE(496, 0) STAGE(480, 2048) STAGE(464, 4096) STAGE(448, 6144)
        WAIT16()

        a0 = (l == 48) ? 1.0 : 0.0;
        a1 = (l == 47) ? 1.0 : 0.0;

        // prime slots 0..7 with chunk-0 LDS rows 15..8 (global 511..504)
        float pb0 = lds[(15 << 7) + 127], pl0 = lds[(15 << 7) + cls1];
        float pb1 = lds[(14 << 7) + 127], pl1 = lds[(14 << 7) + cls1];
        float pb2 = lds[(13 << 7) + 127], pl2 = lds[(13 << 7) + cls1];
        float pb3 = lds[(12 << 7) + 127], pl3 = lds[(12 << 7) + cls1];
        float pb4 = lds[(11 << 7) + 127], pl4 = lds[(11 << 7) + cls1];
        float pb5 = lds[(10 << 7) + 127], pl5 = lds[(10 << 7) + cls1];
        float pb6 = lds[(9 << 7) + 127],  pl6 = lds[(9 << 7) + cls1];
        float pb7 = lds[(8 << 7) + 127],  pl7 = lds[(8 << 7) + cls1];

#define BSTEP(PB, PL, LID, dopf)                                     \
    {                                                                \
        float nb_ = 0.0f, nl_ = 0.0f;                                \
        if (dopf) { nb_ = lds[(LID) + 127];                          \
                    nl_ = lds[(LID) + cls1]; }                       \
        float f0_ = (PB) + EPSf;                                     \
        float f1_ = lab_ok ? (PL) + EPSf : 0.0f;                     \
        double p0 = (double)f0_;                                     \
        double p1 = (double)f1_;                                     \
        double g0 = a0 * p0;                                         \
        double g1 = a1 * p1;                                         \
        double pre = fma(mA, g1, g0);                                \
        double up = dpp64_f0<0x130>(pre);                            \
        a0 = g0 + g1;                                                \
        a1 = g1 + up;                                                \
        if (dopf) { (PB) = nb_; (PL) = nl_; }                        \
    }

        // chunk c steps r=0..15 (slot r&7), consume LDS row 15-r at IB;
        // r<8 pf IB row 7-r ; r>=8 pf INX row 23-r
#define B16(IB, INX)                                                 \
        BSTEP(pb0, pl0, (IB) + (7 << 7), true)                       \
        BSTEP(pb1, pl1, (IB) + (6 << 7), true)                       \
        BSTEP(pb2, pl2, (IB) + (5 << 7), true)                       \
        BSTEP(pb3, pl3, (IB) + (4 << 7), true)                       \
        BSTEP(pb4, pl4, (IB) + (3 << 7), true)                       \
        BSTEP(pb5, pl5, (IB) + (2 << 7), true)                       \
        BSTEP(pb6, pl6, (IB) + (1 << 7), true)                       \
        BSTEP(pb7, pl7, (IB) + (0 << 7), true)                       \
        BSTEP(pb0, pl0, (INX) + (15 << 7), true)                     \
        BSTEP(pb1, pl1, (INX) + (14 << 7), true)                     \
        BSTEP(pb2, pl2, (INX) + (13 << 7), true)                     \
        BSTEP(pb3, pl3, (INX) + (12 << 7), true)                     \
        BSTEP(pb4, pl4, (INX) + (11 << 7), true)                     \
        BSTEP(pb5, pl5, (INX) + (10 << 7), true)                     \
        BSTEP(pb6, pl6, (INX) + (9 << 7), true)                      \
        BSTEP(pb7, pl7, (INX) + (8 << 7), true)                      \
        RENORM64()

        B16(0, 2048)                 // chunk 0
        STAGE(432, 0) WAIT16()

        for (int c = 1; c <= 11; ++c) {
            const int ib  = (c & 3) << 11;
            const int inx = ((c + 1) & 3) << 11;
            B16(ib, inx)
            STAGE(496 - 16 * (c + 4), ib)
            WAIT16()
        }
        B16(0 << 11, 1 << 11)        // chunk 12
        WAIT8()
        B16(1 << 11, 2 << 11)        // chunk 13
        WAIT0()
        B16(2 << 11, 3 << 11)        // chunk 14
        {                            // chunk 15: global rows 271..256
            const int ib = 3 << 11;
            BSTEP(pb0, pl0, ib + (7 << 7), true)
            BSTEP(pb1, pl1, ib + (6 << 7), true)
            BSTEP(pb2, pl2, ib + (5 << 7), true)
            BSTEP(pb3, pl3, ib + (4 << 7), true)
            BSTEP(pb4, pl4, ib + (3 << 7), true)
            BSTEP(pb5, pl5, ib + (2 << 7), true)
            BSTEP(pb6, pl6, ib + (1 << 7), true)
            BSTEP(pb7, pl7, ib + (0 << 7), true)
            BSTEP(pb0, pl0, 0, false)
            BSTEP(pb1, pl1, 0, false)
            BSTEP(pb2, pl2, 0, false)
            BSTEP(pb3, pl3, 0, false)
            BSTEP(pb4, pl4, 0, false)
            BSTEP(pb5, pl5, 0, false)
            BSTEP(pb6, pl6, 0, false)
            BSTEP(pb7, pl7, 0, false)
            RENORM64()
        }
#undef BSTEP
#undef B16

        xb0d[l] = a0; xb1d[l] = a1;
        if (l == 0) xEbs = E;
    }

    __syncthreads();

    if (w == 0) {
        double c = a0 * xb0d[l] + a1 * xb1d[l];
        c += dpp64_f0<0x111>(c);
        c += dpp64_f0<0x112>(c);
        c += dpp64_f0<0x114>(c);
        c += dpp64_f0<0x118>(c);
        if ((l & 15) == 15) rsumd[l >> 4] = c;
        if (l == 0) {
            double s = rsumd[0] + rsumd[1] + rsumd[2] + rsumd[3];
            long long sb = __double_as_longlong(s);
            int se = (int)((sb >> 52) & 0x7FF) - 1022;
            double m = __longlong_as_double((sb & 0x800FFFFFFFFFFFFFLL) | (1022LL << 52));
            float lg = __log2f((float)m) + (float)(se + E + xEbs);
            out[b] = -LN2f * lg;
        }
    }
#undef STAGE
#undef WAIT16
#undef WAIT8
#undef WAIT0
#undef RENORM64
}

extern "C" void kernel_launch(void* const* d_in, const int* in_sizes, int n_in,
                              void* d_out, int out_size, void* d_ws, size_t ws_size,
                              hipStream_t stream) {
    const int*   yt  = (const int*)d_in[0];
    const float* yp  = (const float*)d_in[1];
    float*       out = (float*)d_out;
    hipLaunchKernelGGL(ctc_fwd, dim3(Bn), dim3(128), 0, stream, yt, yp, out);
}